// Round 5
// baseline (423.845 us; speedup 1.0000x reference)
//
#include <hip/hip_runtime.h>

// Problem constants (match reference)
#define NB   8
#define NN   256
#define NM   32
#define NHW  32768

#define CCH    64
#define CSLAB  (NHW / CCH)     // 512 c per (b,ch)
#define KC     32              // c per kstep
#define KSTEPS (CSLAB / KC)    // 16

// ws layout (floats) -- every cell written exactly once, no memset needed
#define OFF_DXP  0                           // [CCH][NB][NN][NM]
#define SZ_DXP   (CCH*NB*NN*NM)
#define OFF_DSP  (OFF_DXP + SZ_DXP)
#define OFF_SNP  (OFF_DSP + SZ_DXP)          // [CCH][NB][NN]
#define SZ_SNP   (CCH*NB*NN)
#define OFF_SSP  (OFF_SNP + SZ_SNP)
#define OFF_STGT (OFF_SSP + SZ_SNP)          // [CCH][NB][NM]

typedef _Float16 half8 __attribute__((ext_vector_type(8)));
typedef float    f32x4 __attribute__((ext_vector_type(4)));

#define MFMA16(a, b, c) __builtin_amdgcn_mfma_f32_16x16x32_f16(a, b, c, 0, 0, 0)

// One kstep's prefetched inputs: 8 + 16 = 24 VGPRs.  All accesses are
// compile-time-indexed (rule #20) so the struct stays in registers.  Two
// named sets (A/B) + 16 acc regs + temps ~= 100 VGPR, under the 128 cap --
// this is R3's pipeline idea at R4's (spill-free) state size.
struct Set {
    float  xv[8];               // X fragment (k = quad*8+j)
    float4 ta, tb, tc, td;      // T fragments (m = l16 / 16+l16)
};

__device__ __forceinline__ void load_set(Set& s, const float* Xk,
                                         const float* Tq0, const float* Tq1) {
#pragma unroll
    for (int j = 0; j < 8; ++j)
        s.xv[j] = Xk[(size_t)j * NN];       // 4 quad-segments x 64 B per instr
    s.ta = *(const float4*)(Tq0);
    s.tb = *(const float4*)(Tq0 + 4);
    s.tc = *(const float4*)(Tq1);
    s.td = *(const float4*)(Tq1 + 4);
}

// ---------------------------------------------------------------------------
// Wave-autonomous MFMA contraction: no LDS, no barriers, 16-n wave tile, and
// (this revision) an explicit 2-deep even/odd register prefetch.  R4 proved
// the spill-free 16n structure matches the old LDS version (~137 us) -- both
// share per-kstep load->consume serialization (each wave alternates ~900cyc
// memory wait with ~430cyc compute; SIMDs idle, VALUBusy ~17%).  Issuing all
// of kstep k+1's vmem before kstep k's compute makes the pre-compute waitcnt
// a counted vmcnt (12 newer loads outstanding), never a drain.
//   Dx[n,m] = sum_c x*t        Ds[n,m] = sum_c sigmoid(x)*t
//   Sn[n]   = sum_c (x + softplus(-x))   Ss[n] = sum_c sigmoid(x)
//   St[m]   = sum_c t
// A-frag (16x16x32 f16): lane holds A[row=lane&15][k=(lane>>4)*8+j]
//   row = n-l16, k = c = quad*8+j  ->  xv[j] = X[c0+ks*32+quad*8+j][n0+l16]
// B-frag: lane holds B[col=lane&15][k] -> T[m=l16][c]
// D: lane reg r -> row(n-offset) = quad*4+r, col(m) = l16
__global__ __launch_bounds__(256, 4) void cost_main(
    const float* __restrict__ X,   // [NB][NHW][NN]
    const float* __restrict__ T,   // [NB][NM][NHW]
    float* __restrict__ ws) {
    const int blk  = blockIdx.x;
    const int b    = blk & 7;                 // XCD-constant per b
    const int rest = blk >> 3;
    const int nb4  = rest & 3;                // n quarter (fastest bit)
    const int ch   = rest >> 2;               // 0..63

    const int tid  = threadIdx.x;
    const int wave = tid >> 6;                // 0..3
    const int lane = tid & 63;
    const int l16  = lane & 15;
    const int quad = lane >> 4;

    const int c0 = ch * CSLAB;
    const int n0 = nb4 * 64 + wave * 16;      // wave-exclusive 16-n stripe

    const float* Xp  = X + ((size_t)(b * NHW + c0 + quad * 8)) * NN + n0 + l16;
    const float* Tq0 = T + ((size_t)b * NM + l16) * NHW + c0 + quad * 8;
    const float* Tq1 = Tq0 + (size_t)16 * NHW;

    f32x4 ax0 = {0.f, 0.f, 0.f, 0.f};   // Dx, m 0..15
    f32x4 ax1 = {0.f, 0.f, 0.f, 0.f};   // Dx, m 16..31
    f32x4 as0 = {0.f, 0.f, 0.f, 0.f};   // Ds, m 0..15
    f32x4 as1 = {0.f, 0.f, 0.f, 0.f};   // Ds, m 16..31
    float sneg = 0.f, ssig = 0.f;
    float ts0 = 0.f, ts1 = 0.f;

    auto compute = [&](const Set& s) {
        half8 ht0 = {(_Float16)s.ta.x, (_Float16)s.ta.y, (_Float16)s.ta.z, (_Float16)s.ta.w,
                     (_Float16)s.tb.x, (_Float16)s.tb.y, (_Float16)s.tb.z, (_Float16)s.tb.w};
        half8 ht1 = {(_Float16)s.tc.x, (_Float16)s.tc.y, (_Float16)s.tc.z, (_Float16)s.tc.w,
                     (_Float16)s.td.x, (_Float16)s.td.y, (_Float16)s.td.z, (_Float16)s.td.w};
        ts0 += (s.ta.x + s.ta.y) + (s.ta.z + s.ta.w) + (s.tb.x + s.tb.y) + (s.tb.z + s.tb.w);
        ts1 += (s.tc.x + s.tc.y) + (s.tc.z + s.tc.w) + (s.td.x + s.td.y) + (s.td.z + s.td.w);
        half8 hx, hs;
#pragma unroll
        for (int j = 0; j < 8; ++j) {
            float x  = s.xv[j];
            float e  = __expf(-fabsf(x));                   // exp(-|x|) <= 1
            float rc = __builtin_amdgcn_rcpf(1.f + e);
            float sg = (x >= 0.f) ? rc : 1.f - rc;          // stable sigmoid
            float pos = fmaxf(-x, 0.f) + __logf(1.f + e);   // softplus(-x)
            sneg += x + pos;
            ssig += sg;
            hx[j] = (_Float16)x;
            hs[j] = (_Float16)sg;
        }
        ax0 = MFMA16(hx, ht0, ax0);
        ax1 = MFMA16(hx, ht1, ax1);
        as0 = MFMA16(hs, ht0, as0);
        as1 = MFMA16(hs, ht1, as1);
    };

    // 2-deep even/odd prefetch, NAMED sets (no runtime indexing).  All vmem
    // for kstep k is issued a full compute-phase before its consumption.
    Set A, B;
    load_set(A, Xp, Tq0, Tq1);
#pragma unroll 1
    for (int it = 0; it < KSTEPS / 2; ++it) {
        const int kb = 2 * it + 1;
        load_set(B, Xp + (size_t)kb * KC * NN, Tq0 + kb * KC, Tq1 + kb * KC);
        compute(A);
        const int ka = 2 * it + 2;
        if (ka < KSTEPS)
            load_set(A, Xp + (size_t)ka * KC * NN, Tq0 + ka * KC, Tq1 + ka * KC);
        compute(B);
    }

    // ---- epilogue: wave-exclusive n-stripes -> plain stores, no reduction ----
    {
        float sn = sneg, ss = ssig;           // 4 quads share n -> quad-reduce
        sn += __shfl_xor(sn, 16); sn += __shfl_xor(sn, 32);
        ss += __shfl_xor(ss, 16); ss += __shfl_xor(ss, 32);
        if (lane < 16) {
            const size_t sb = ((size_t)ch * NB + b) * NN + n0 + l16;
            ws[OFF_SNP + sb] = sn;
            ws[OFF_SSP + sb] = ss;
        }
    }
    if (wave == 0 && nb4 == 0) {              // ts identical across waves/quarters
        float t0 = ts0, t1 = ts1;
        t0 += __shfl_xor(t0, 16); t0 += __shfl_xor(t0, 32);
        t1 += __shfl_xor(t1, 16); t1 += __shfl_xor(t1, 32);
        if (lane < 16) {
            const size_t tb_ = ((size_t)ch * NB + b) * NM;
            ws[OFF_STGT + tb_ + l16]      = t0;
            ws[OFF_STGT + tb_ + l16 + 16] = t1;
        }
    }
    const size_t dbase = ((size_t)ch * NB + b) * NN * NM;
#pragma unroll
    for (int r = 0; r < 4; ++r) {
        const int n = n0 + quad * 4 + r;
        const size_t o = dbase + (size_t)n * NM;
        ws[OFF_DXP + o + l16]      = ax0[r];
        ws[OFF_DXP + o + l16 + 16] = ax1[r];
        ws[OFF_DSP + o + l16]      = as0[r];
        ws[OFF_DSP + o + l16 + 16] = as1[r];
    }
}

// ---------------------------------------------------------------------------
// Combine 64 chunk partials + class/center/dice formula.
// One block per (b,n) -> 2048 blocks (8/CU), 8-way ch-split + LDS tree.
__global__ __launch_bounds__(256) void cost_finalize(
    const float* __restrict__ P,    // [NB][NN][1]
    const float* __restrict__ CD,   // [NB][NN][NM]
    const int*   __restrict__ LAB,  // [NB][NM]
    const float* __restrict__ ws,
    float* __restrict__ out) {
    const int bn = blockIdx.x;            // b*NN + n
    const int n  = bn & 255;
    const int b  = bn >> 8;
    const int t  = threadIdx.x;
    const int m  = t & 31;
    const int q  = t >> 5;                // 0..7 : ch octet

    float dx = 0.f, ds = 0.f, sn = 0.f, ss = 0.f, st = 0.f;
#pragma unroll
    for (int k = 0; k < 8; ++k) {
        const int ch = q * 8 + k;
        const size_t e = (size_t)ch * NB + b;
        const size_t o = (e * NN + n) * NM + m;
        dx += ws[OFF_DXP + o];
        ds += ws[OFF_DSP + o];
        sn += ws[OFF_SNP + e * NN + n];
        ss += ws[OFF_SSP + e * NN + n];
        st += ws[OFF_STGT + e * NM + m];
    }

    __shared__ float red[5][8][32];
    red[0][q][m] = dx; red[1][q][m] = ds; red[2][q][m] = sn;
    red[3][q][m] = ss; red[4][q][m] = st;
    __syncthreads();

    if (t < 32) {                          // t == m here
        float a0 = 0.f, a1 = 0.f, a2 = 0.f, a3 = 0.f, a4 = 0.f;
#pragma unroll
        for (int k = 0; k < 8; ++k) {
            a0 += red[0][k][m]; a1 += red[1][k][m]; a2 += red[2][k][m];
            a3 += red[3][k][m]; a4 += red[4][k][m];
        }
        const float p   = P[bn];
        const int   lab = LAB[b * NM + m];
        const float cls = lab ? -p : (p - 1.f);

        const float cmask = (a2 - a0) * (1.f / (float)NHW);
        const float dice  = 1.f - (2.f * a1 + 1.f) / (a3 + a4 + 1.f);

        const size_t o = (size_t)bn * NM + m;
        out[o] = 2.f * cls + CD[o] + 5.f * cmask + 2.f * dice;
    }
}

// ---------------------------------------------------------------------------
extern "C" void kernel_launch(void* const* d_in, const int* in_sizes, int n_in,
                              void* d_out, int out_size, void* d_ws, size_t ws_size,
                              hipStream_t stream) {
    const float* P   = (const float*)d_in[0];  // sem_cls_prob
    const float* CD  = (const float*)d_in[1];  // center_dist
    const float* X   = (const float*)d_in[2];  // mask_heatmaps
    const float* T   = (const float*)d_in[3];  // mask_tgt
    const int*   LAB = (const int*)d_in[4];    // gt_plane_sem_cls_label
    float* out = (float*)d_out;
    float* ws  = (float*)d_ws;

    hipLaunchKernelGGL(cost_main, dim3(NB * CCH * 4), dim3(256), 0, stream, X, T, ws);
    hipLaunchKernelGGL(cost_finalize, dim3(NB * NN), dim3(256), 0, stream,
                       P, CD, LAB, ws, out);
}

// Round 6
// 411.790 us; speedup vs baseline: 1.0293x; 1.0293x over previous
//
#include <hip/hip_runtime.h>

// Problem constants (match reference)
#define NB   8
#define NN   256
#define NM   32
#define NHW  32768

#define CCH    64
#define CSLAB  (NHW / CCH)     // 512 c per (b,ch)
#define KC     32              // c per kstep
#define KSTEPS (CSLAB / KC)    // 16

// ws layout (floats) -- every cell written exactly once, no memset needed
#define OFF_DXP  0                           // [CCH][NB][NN][NM]
#define SZ_DXP   (CCH*NB*NN*NM)
#define OFF_DSP  (OFF_DXP + SZ_DXP)
#define OFF_SNP  (OFF_DSP + SZ_DXP)          // [CCH][NB][NN]
#define SZ_SNP   (CCH*NB*NN)
#define OFF_SSP  (OFF_SNP + SZ_SNP)
#define OFF_STGT (OFF_SSP + SZ_SNP)          // [CCH][NB][NM]

typedef _Float16 half8 __attribute__((ext_vector_type(8)));
typedef float    f32x4 __attribute__((ext_vector_type(4)));

#define MFMA16(a, b, c) __builtin_amdgcn_mfma_f32_16x16x32_f16(a, b, c, 0, 0, 0)

// ---------------------------------------------------------------------------
// Wave-autonomous MFMA contraction -- no LDS, no barriers.  This revision
// attacks the measured 2.4 TB/s wall (main ~137us across FOUR structures):
//  (H1) b moved to HIGH blockIdx bits: the old `b = blk & 7` + round-robin
//       block->XCD dispatch pinned each XCD to a disjoint 32 MB X slice,
//       capping the device at 8x(per-XCD ingress).  Now every XCD streams
//       from the full range.
//  (H3) 32-n wave tile (f=0/1 halves): each X cache line (128 B) is fully
//       consumed by ONE wave in one kstep, instead of split across two
//       unsynchronized waves (64 B each).
// Register budget (R3's spill lesson): 32 acc + 32 per-kstep inputs + temps
// ~= 85 live VGPRs with unroll 1 -- safely under the 128 cap of (256,4).
// ILP was proven a non-factor (R5's counted-vmcnt prefetch == serial), so
// no register double-buffer.
//   Dx[n,m] = sum_c x*t        Ds[n,m] = sum_c sigmoid(x)*t
//   Sn[n]   = sum_c (x + softplus(-x))   Ss[n] = sum_c sigmoid(x)
//   St[m]   = sum_c t
// A-frag (16x16x32 f16): lane holds A[row=lane&15][k=(lane>>4)*8+j]
//   row = n-l16, k = c = quad*8+j  ->  x = X[c0+ks*32+quad*8+j][n0+f*16+l16]
// B-frag: lane holds B[col=lane&15][k] -> T[m=l16][c]
// D: lane reg r -> row(n-offset) = quad*4+r, col(m) = l16
__global__ __launch_bounds__(256, 4) void cost_main(
    const float* __restrict__ X,   // [NB][NHW][NN]
    const float* __restrict__ T,   // [NB][NM][NHW]
    float* __restrict__ ws) {
    const int blk  = blockIdx.x;               // [b:3][ch:6][half:1]
    const int b    = blk >> 7;                 // HIGH bits: XCD-de-pinned
    const int rest = blk & 127;
    const int ch   = rest >> 1;                // 0..63
    const int half = rest & 1;                 // n-half of the row

    const int tid  = threadIdx.x;
    const int wave = tid >> 6;                 // 0..3
    const int lane = tid & 63;
    const int l16  = lane & 15;
    const int quad = lane >> 4;

    const int c0 = ch * CSLAB;
    const int n0 = half * 128 + wave * 32;     // wave-exclusive 32-n stripe

    const float* Xp  = X + ((size_t)(b * NHW + c0 + quad * 8)) * NN + n0 + l16;
    const float* Tq0 = T + ((size_t)b * NM + l16) * NHW + c0 + quad * 8;
    const float* Tq1 = Tq0 + (size_t)16 * NHW;

    f32x4 ax0[2], ax1[2], as0[2], as1[2];
#pragma unroll
    for (int f = 0; f < 2; ++f) {
        ax0[f] = f32x4{0.f, 0.f, 0.f, 0.f};
        ax1[f] = f32x4{0.f, 0.f, 0.f, 0.f};
        as0[f] = f32x4{0.f, 0.f, 0.f, 0.f};
        as1[f] = f32x4{0.f, 0.f, 0.f, 0.f};
    }
    float sneg[2] = {0.f, 0.f};
    float ssig[2] = {0.f, 0.f};
    float ts0 = 0.f, ts1 = 0.f;

#pragma unroll 1
    for (int ks = 0; ks < KSTEPS; ++ks) {
        const float* Xk = Xp + (size_t)ks * KC * NN;
        // All 20 loads up front, independent -> compiler issues them
        // back-to-back; 12-16 waves/CU provide the latency cover.
        float xa[8], xb[8];
#pragma unroll
        for (int j = 0; j < 8; ++j) {
            xa[j] = Xk[(size_t)j * NN];        // n0+l16      (64 B of line)
            xb[j] = Xk[(size_t)j * NN + 16];   // n0+16+l16   (other 64 B)
        }
        float4 ta = *(const float4*)(Tq0 + ks * KC);
        float4 tb = *(const float4*)(Tq0 + ks * KC + 4);
        float4 tc = *(const float4*)(Tq1 + ks * KC);
        float4 td = *(const float4*)(Tq1 + ks * KC + 4);

        half8 ht0 = {(_Float16)ta.x, (_Float16)ta.y, (_Float16)ta.z, (_Float16)ta.w,
                     (_Float16)tb.x, (_Float16)tb.y, (_Float16)tb.z, (_Float16)tb.w};
        half8 ht1 = {(_Float16)tc.x, (_Float16)tc.y, (_Float16)tc.z, (_Float16)tc.w,
                     (_Float16)td.x, (_Float16)td.y, (_Float16)td.z, (_Float16)td.w};
        ts0 += (ta.x + ta.y) + (ta.z + ta.w) + (tb.x + tb.y) + (tb.z + tb.w);
        ts1 += (tc.x + tc.y) + (tc.z + tc.w) + (td.x + td.y) + (td.z + td.w);

#pragma unroll
        for (int f = 0; f < 2; ++f) {
            half8 hx, hs;
#pragma unroll
            for (int j = 0; j < 8; ++j) {
                float x  = f ? xb[j] : xa[j];               // static select
                float e  = __expf(-fabsf(x));                   // exp(-|x|) <= 1
                float rc = __builtin_amdgcn_rcpf(1.f + e);
                float sg = (x >= 0.f) ? rc : 1.f - rc;          // stable sigmoid
                float pos = fmaxf(-x, 0.f) + __logf(1.f + e);   // softplus(-x)
                sneg[f] += x + pos;
                ssig[f] += sg;
                hx[j] = (_Float16)x;
                hs[j] = (_Float16)sg;
            }
            ax0[f] = MFMA16(hx, ht0, ax0[f]);
            ax1[f] = MFMA16(hx, ht1, ax1[f]);
            as0[f] = MFMA16(hs, ht0, as0[f]);
            as1[f] = MFMA16(hs, ht1, as1[f]);
        }
    }

    // ---- epilogue: wave-exclusive n-stripes -> plain stores, no reduction ----
#pragma unroll
    for (int f = 0; f < 2; ++f) {
        float sn = sneg[f], ss = ssig[f];     // 4 quads share n -> quad-reduce
        sn += __shfl_xor(sn, 16); sn += __shfl_xor(sn, 32);
        ss += __shfl_xor(ss, 16); ss += __shfl_xor(ss, 32);
        if (lane < 16) {
            const size_t sb = ((size_t)ch * NB + b) * NN + n0 + f * 16 + l16;
            ws[OFF_SNP + sb] = sn;
            ws[OFF_SSP + sb] = ss;
        }
    }
    if (wave == 0 && half == 0) {             // ts identical across waves/halves
        float t0 = ts0, t1 = ts1;
        t0 += __shfl_xor(t0, 16); t0 += __shfl_xor(t0, 32);
        t1 += __shfl_xor(t1, 16); t1 += __shfl_xor(t1, 32);
        if (lane < 16) {
            const size_t tb_ = ((size_t)ch * NB + b) * NM;
            ws[OFF_STGT + tb_ + l16]      = t0;
            ws[OFF_STGT + tb_ + l16 + 16] = t1;
        }
    }
    const size_t dbase = ((size_t)ch * NB + b) * NN * NM;
#pragma unroll
    for (int f = 0; f < 2; ++f) {
#pragma unroll
        for (int r = 0; r < 4; ++r) {
            const int n = n0 + f * 16 + quad * 4 + r;
            const size_t o = dbase + (size_t)n * NM;
            ws[OFF_DXP + o + l16]      = ax0[f][r];
            ws[OFF_DXP + o + l16 + 16] = ax1[f][r];
            ws[OFF_DSP + o + l16]      = as0[f][r];
            ws[OFF_DSP + o + l16 + 16] = as1[f][r];
        }
    }
}

// ---------------------------------------------------------------------------
// Combine 64 chunk partials + class/center/dice formula.
// One block per (b,n) -> 2048 blocks (8/CU), 8-way ch-split + LDS tree.
__global__ __launch_bounds__(256) void cost_finalize(
    const float* __restrict__ P,    // [NB][NN][1]
    const float* __restrict__ CD,   // [NB][NN][NM]
    const int*   __restrict__ LAB,  // [NB][NM]
    const float* __restrict__ ws,
    float* __restrict__ out) {
    const int bn = blockIdx.x;            // b*NN + n
    const int n  = bn & 255;
    const int b  = bn >> 8;
    const int t  = threadIdx.x;
    const int m  = t & 31;
    const int q  = t >> 5;                // 0..7 : ch octet

    float dx = 0.f, ds = 0.f, sn = 0.f, ss = 0.f, st = 0.f;
#pragma unroll
    for (int k = 0; k < 8; ++k) {
        const int ch = q * 8 + k;
        const size_t e = (size_t)ch * NB + b;
        const size_t o = (e * NN + n) * NM + m;
        dx += ws[OFF_DXP + o];
        ds += ws[OFF_DSP + o];
        sn += ws[OFF_SNP + e * NN + n];
        ss += ws[OFF_SSP + e * NN + n];
        st += ws[OFF_STGT + e * NM + m];
    }

    __shared__ float red[5][8][32];
    red[0][q][m] = dx; red[1][q][m] = ds; red[2][q][m] = sn;
    red[3][q][m] = ss; red[4][q][m] = st;
    __syncthreads();

    if (t < 32) {                          // t == m here
        float a0 = 0.f, a1 = 0.f, a2 = 0.f, a3 = 0.f, a4 = 0.f;
#pragma unroll
        for (int k = 0; k < 8; ++k) {
            a0 += red[0][k][m]; a1 += red[1][k][m]; a2 += red[2][k][m];
            a3 += red[3][k][m]; a4 += red[4][k][m];
        }
        const float p   = P[bn];
        const int   lab = LAB[b * NM + m];
        const float cls = lab ? -p : (p - 1.f);

        const float cmask = (a2 - a0) * (1.f / (float)NHW);
        const float dice  = 1.f - (2.f * a1 + 1.f) / (a3 + a4 + 1.f);

        const size_t o = (size_t)bn * NM + m;
        out[o] = 2.f * cls + CD[o] + 5.f * cmask + 2.f * dice;
    }
}

// ---------------------------------------------------------------------------
extern "C" void kernel_launch(void* const* d_in, const int* in_sizes, int n_in,
                              void* d_out, int out_size, void* d_ws, size_t ws_size,
                              hipStream_t stream) {
    const float* P   = (const float*)d_in[0];  // sem_cls_prob
    const float* CD  = (const float*)d_in[1];  // center_dist
    const float* X   = (const float*)d_in[2];  // mask_heatmaps
    const float* T   = (const float*)d_in[3];  // mask_tgt
    const int*   LAB = (const int*)d_in[4];    // gt_plane_sem_cls_label
    float* out = (float*)d_out;
    float* ws  = (float*)d_ws;

    hipLaunchKernelGGL(cost_main, dim3(NB * CCH * 2), dim3(256), 0, stream, X, T, ws);
    hipLaunchKernelGGL(cost_finalize, dim3(NB * NN), dim3(256), 0, stream,
                       P, CD, LAB, ws, out);
}